// Round 12
// baseline (264.546 us; speedup 1.0000x reference)
//
#include <hip/hip_runtime.h>
#include <hip/hip_bf16.h>

#define B_   4
#define IC   64
#define OC   128
#define HH   128
#define WW   128
#define HP   130      // padded H/W for sampling
#define XOF  384      // x_off spatial (128*3)
#define XPAD 388      // padded x-dim of granule layout
#define OH2  382      // final output spatial

typedef __attribute__((ext_vector_type(4))) float f32x4;
typedef __attribute__((ext_vector_type(8))) __bf16 bf16x8;
typedef __attribute__((ext_vector_type(8))) unsigned short us8;
typedef __attribute__((ext_vector_type(4), aligned(4))) float f32x4u;

__device__ __forceinline__ void gload16(const void* gsrc, void* ldst) {
    __builtin_amdgcn_global_load_lds(
        (const __attribute__((address_space(1))) void*)gsrc,
        (__attribute__((address_space(3))) void*)ldst, 16, 0, 0);
}

// ---------------------------------------------------------------------------
// Kernel T (byte-identical to R11): NCHW -> NHWC fp32 transpose of x.
// ---------------------------------------------------------------------------
__global__ __launch_bounds__(256) void nchw2nhwc(const float* __restrict__ x,
                                                 float* __restrict__ xt) {
    __shared__ float tile[64][33];
    int bid = blockIdx.x;              // 4*128*4 = 2048
    int xt4 = bid & 3;
    int y   = (bid >> 2) & 127;
    int b   = bid >> 9;
    int x0  = xt4 * 32;

    int t  = threadIdx.x;
    int xl = t & 31;
    int c8 = t >> 5;
#pragma unroll
    for (int it = 0; it < 8; ++it) {
        int c = it * 8 + c8;
        tile[c][xl] = x[(((size_t)b * IC + c) * HH + y) * WW + x0 + xl];
    }
    __syncthreads();
    int c  = t & 63;
    int xw = t >> 6;
#pragma unroll
    for (int it = 0; it < 8; ++it) {
        int xx = it * 4 + xw;
        xt[(((size_t)b * HH + y) * WW + x0 + xx) * IC + c] = tile[c][xx];
    }
}

// ---------------------------------------------------------------------------
// Kernel A v5 (byte-identical to R11): offset conv, ic-split x4 + LDS reduce,
// readfirstlane-scalarized weight base.
// ---------------------------------------------------------------------------
__global__ __launch_bounds__(256) void offset_lds4(const float* __restrict__ x,
                                                   const float* __restrict__ w_p,
                                                   const float* __restrict__ b_p,
                                                   float* __restrict__ off) {
    __shared__ float part[4][64][18];

    int t   = threadIdx.x;
    int pxl = t & 63;
    int icq = t >> 6;                 // 0..3 == wave index
    int seg = blockIdx.x & 1;
    int row = blockIdx.x >> 1;
    int py  = row & 127;
    int b   = row >> 7;
    int px  = seg * 64 + pxl;
    int ic0 = __builtin_amdgcn_readfirstlane(icq << 4);   // wave-uniform SGPR

    float acc[18];
#pragma unroll
    for (int co = 0; co < 18; ++co) acc[co] = 0.f;

    const float* xb = x + ((size_t)b * IC + ic0) * HH * WW;

    for (int ci = 0; ci < 16; ++ci) {
        const float* xc = xb + (size_t)ci * HH * WW;
        float xv[9];
#pragma unroll
        for (int ky = 0; ky < 3; ++ky) {
            int yy = py + ky - 1;
            bool yok = (yy >= 0) && (yy < HH);
#pragma unroll
            for (int kx = 0; kx < 3; ++kx) {
                int xx = px + kx - 1;
                bool ok = yok && (xx >= 0) && (xx < WW);
                xv[ky * 3 + kx] = ok ? xc[yy * WW + xx] : 0.f;
            }
        }
#pragma unroll
        for (int co = 0; co < 18; ++co) {
            const float* wrow = w_p + ((size_t)co * IC + ic0 + ci) * 9;
            f32x4u w0 = *(const f32x4u*)wrow;
            f32x4u w1 = *(const f32x4u*)(wrow + 4);
            float  w8 = wrow[8];
            acc[co] = fmaf(w0.x, xv[0], acc[co]);
            acc[co] = fmaf(w0.y, xv[1], acc[co]);
            acc[co] = fmaf(w0.z, xv[2], acc[co]);
            acc[co] = fmaf(w0.w, xv[3], acc[co]);
            acc[co] = fmaf(w1.x, xv[4], acc[co]);
            acc[co] = fmaf(w1.y, xv[5], acc[co]);
            acc[co] = fmaf(w1.z, xv[6], acc[co]);
            acc[co] = fmaf(w1.w, xv[7], acc[co]);
            acc[co] = fmaf(w8,   xv[8], acc[co]);
        }
    }

#pragma unroll
    for (int co = 0; co < 18; ++co) part[icq][pxl][co] = acc[co];
    __syncthreads();

    for (int co = icq; co < 18; co += 4) {
        float s = b_p[co] + part[0][pxl][co] + part[1][pxl][co]
                          + part[2][pxl][co] + part[3][pxl][co];
        off[((size_t)b * 18 + co) * HH * WW + (size_t)py * WW + px] = s;
    }
}

// ---------------------------------------------------------------------------
// Kernel P (byte-identical): weights -> bf16 K-step tiles.
// ---------------------------------------------------------------------------
__global__ __launch_bounds__(256) void prep_w(const float* __restrict__ wc,
                                              unsigned short* __restrict__ Bt) {
    int t = blockIdx.x * 256 + threadIdx.x;
    if (t >= 18 * 4 * 128 * 8) return;
    int e  = t & 7;
    int oc = (t >> 3) & 127;
    int kg = (t >> 10) & 3;
    int s  = t >> 12;
    int ic = ((s & 1) << 5) + (kg << 3) + e;
    int kpos = s >> 1;
    int ky = kpos / 3, kx = kpos % 3;
    float v = wc[(((size_t)oc * IC + ic) * 3 + ky) * 3 + kx];
    __hip_bfloat16 h = __float2bfloat16(v);
    Bt[t] = reinterpret_cast<unsigned short&>(h);
}

// ---------------------------------------------------------------------------
// Kernel B v3 (byte-identical to R11): bilinear sampling from NHWC x.
// ---------------------------------------------------------------------------
__global__ __launch_bounds__(256) void sample_nhwc(const float* __restrict__ xt,
                                                   const float* __restrict__ off,
                                                   unsigned short* __restrict__ xoff,
                                                   int b0, int nwg) {
    int orig = blockIdx.x;
    int chunk = nwg >> 3;
    int wg = (orig & 7) * chunk + (orig >> 3);

    int xtile = wg % 12;
    int tmp = wg / 12;
    int yy  = tmp % XOF;
    int bl  = tmp / XOF;
    int b   = b0 + bl;
    int xx0 = xtile * 32;

    int t  = threadIdx.x;
    int xl = t & 31;
    int cg = t >> 5;
    int xx = xx0 + xl;

    int j = xx / 3, kw = xx % 3;
    int i = yy / 3, kh = yy % 3;
    int n = kh * 3 + kw;

    const float* offb = off + (size_t)b * 18 * HH * WW + (size_t)i * WW + j;
    float offr = offb[(size_t)n * HH * WW];
    float offc = offb[(size_t)(n + 9) * HH * WW];

    float pr = (float)(i + kh) + offr;
    float pc = (float)(j + kw) + offc;

    float r0f = floorf(pr), c0f = floorf(pc);
    int r0 = min(max((int)r0f, 0), HP - 1);
    int c0 = min(max((int)c0f, 0), HP - 1);
    int r1 = min(max((int)(r0f + 1.f), 0), HP - 1);
    int c1 = min(max((int)(c0f + 1.f), 0), HP - 1);

    float prc = fminf(fmaxf(pr, 0.f), (float)(HP - 1));
    float pcc = fminf(fmaxf(pc, 0.f), (float)(HP - 1));

    float R0 = 1.f + ((float)r0 - prc);
    float R1 = 1.f - ((float)r1 - prc);
    float C0 = 1.f + ((float)c0 - pcc);
    float C1 = 1.f - ((float)c1 - pcc);

    int rr0 = r0 - 1, cc0 = c0 - 1, rr1 = r1 - 1, cc1 = c1 - 1;
    if (!(rr0 >= 0 && rr0 < HH)) R0 = 0.f;
    if (!(rr1 >= 0 && rr1 < HH)) R1 = 0.f;
    float C0m = (cc0 >= 0 && cc0 < WW) ? C0 : 0.f;
    float C1m = (cc1 >= 0 && cc1 < WW) ? C1 : 0.f;
    int ra0 = min(max(rr0, 0), HH - 1);
    int ra1 = min(max(rr1, 0), HH - 1);
    int ca0 = min(max(cc0, 0), WW - 1);
    int ca1 = min(max(cc1, 0), WW - 1);

    const float* xb = xt + (size_t)b * HH * WW * IC + cg * 8;
    const float* p00 = xb + ((size_t)ra0 * WW + ca0) * IC;
    const float* p01 = xb + ((size_t)ra0 * WW + ca1) * IC;
    const float* p10 = xb + ((size_t)ra1 * WW + ca0) * IC;
    const float* p11 = xb + ((size_t)ra1 * WW + ca1) * IC;

    us8 res;
#pragma unroll
    for (int h = 0; h < 2; ++h) {
        f32x4u a  = *(const f32x4u*)(p00 + h * 4);
        f32x4u bb = *(const f32x4u*)(p01 + h * 4);
        f32x4u cc = *(const f32x4u*)(p10 + h * 4);
        f32x4u dd = *(const f32x4u*)(p11 + h * 4);
#pragma unroll
        for (int e = 0; e < 4; ++e) {
            float v = R0 * (C0m * a[e] + C1m * bb[e]) +
                      R1 * (C0m * cc[e] + C1m * dd[e]);
            __hip_bfloat16 hh = __float2bfloat16(v);
            res[h * 4 + e] = reinterpret_cast<unsigned short&>(hh);
        }
    }

    size_t di = ((((size_t)bl * XOF + yy) * 8 + cg) * XPAD + xx) * 8;
    *(us8*)(xoff + di) = res;
}

// ---------------------------------------------------------------------------
// Kernel C v6: BARRIER-FREE bf16 MFMA implicit-GEMM conv.
// Each wave owns a private A LDS region ([wave:4][buf:2][cg:4][128px][16B]
// = 64KB total) and stages exactly what it reads (wm-pair duplication is
// L2-hot, issue-only cost). Zero __syncthreads: per-wave ordering via one
// explicit s_waitcnt vmcnt(0) per slab swap (waits only this wave's 8 A
// gloads, issued 3 K-steps earlier). B fragments register-prefetched from
// L2 as in v5. Waves run fully self-paced.
// ---------------------------------------------------------------------------
__global__ __launch_bounds__(256) void conv2_mfma(const unsigned short* __restrict__ xoff,
                                                  const unsigned short* __restrict__ Bt,
                                                  float* __restrict__ out,
                                                  int b0, int nwg) {
    __shared__ __align__(16) char lds[65536];

    // bijective XCD-chunk swizzle (m204)
    int orig = blockIdx.x;
    int q = nwg >> 3, r = nwg & 7;
    int xcd = orig & 7, loc = orig >> 3;
    int wgid = (xcd < r ? xcd * (q + 1) : r * (q + 1) + (xcd - r) * q) + loc;

    int xt  = wgid % 3;
    int tmp = wgid / 3;
    int oy  = tmp % OH2;
    int bl  = tmp / OH2;
    int x0  = xt << 7;

    int tid  = threadIdx.x;
    int wave = tid >> 6, lane = tid & 63;
    int wm = wave >> 1;            // px half
    int wn = wave & 1;             // oc half
    int lr = lane & 15, lc = lane >> 4;

    const char* xb = (const char*)xoff + (size_t)bl * ((size_t)XOF * 8 * XPAD * 16);
    const char* bt = (const char*)Bt;
    const int boff = ((lc * 128) + wn * 64 + lr) * 16;
    char* waveLds = lds + wave * 16384;

    f32x4 acc[4][4];
#pragma unroll
    for (int mf = 0; mf < 4; ++mf)
#pragma unroll
        for (int nf = 0; nf < 4; ++nf)
            acc[mf][nf] = (f32x4){0.f, 0.f, 0.f, 0.f};

    // stage this wave's private A slab for super-step s6: 8 gloads,
    // covering global px [x0+wm*64, x0+wm*64+128).
    auto stageA = [&](int abuf, int s6) {
        int ky  = s6 >> 1;
        int ich = s6 & 1;
#pragma unroll
        for (int cg = 0; cg < 4; ++cg)
#pragma unroll
            for (int seg = 0; seg < 2; ++seg) {
                const char* src = xb +
                    (((size_t)(oy + ky) * 8 + ich * 4 + cg) * XPAD +
                     x0 + wm * 64 + seg * 64 + lane) * 16;
                gload16(src, waveLds + abuf * 8192 + (cg * 2 + seg) * 1024);
            }
    };

    auto loadB = [&](bf16x8* dst, int t) {
        int s6 = t / 3, kx = t % 3;
        int sB = ((s6 >> 1) * 3 + kx) * 2 + (s6 & 1);
        const char* bsrc = bt + (size_t)sB * 8192 + boff;
#pragma unroll
        for (int nf = 0; nf < 4; ++nf)
            dst[nf] = *(const bf16x8*)(bsrc + nf * 256);
    };

    bf16x8 bcur[4], bnxt[4];

    stageA(0, 0);
    loadB(bcur, 0);

    int abuf = 0;
    for (int s6 = 0; s6 < 6; ++s6) {
        // wait for THIS wave's slab(s6) gloads (the only outstanding vmem:
        // B prefetch was drained by its register use last step).
        asm volatile("s_waitcnt vmcnt(0)" ::: "memory");
        __builtin_amdgcn_sched_barrier(0);
        if (s6 + 1 < 6) stageA(abuf ^ 1, s6 + 1);
#pragma unroll
        for (int kx = 0; kx < 3; ++kx) {
            int t = s6 * 3 + kx;
            if (t + 1 < 18) loadB(bnxt, t + 1);
            const char* abase = waveLds + abuf * 8192;
            bf16x8 af[4];
#pragma unroll
            for (int mf = 0; mf < 4; ++mf)
                af[mf] = *(const bf16x8*)(abase + lc * 2048 + (mf * 16 + lr + kx) * 16);
#pragma unroll
            for (int mf = 0; mf < 4; ++mf)
#pragma unroll
                for (int nf = 0; nf < 4; ++nf)
                    acc[mf][nf] = __builtin_amdgcn_mfma_f32_16x16x32_bf16(
                        af[mf], bcur[nf], acc[mf][nf], 0, 0, 0);
#pragma unroll
            for (int nf = 0; nf < 4; ++nf) bcur[nf] = bnxt[nf];
        }
        abuf ^= 1;
    }

    int b = b0 + bl;
#pragma unroll
    for (int mf = 0; mf < 4; ++mf) {
        int ox0 = x0 + wm * 64 + mf * 16 + (lc << 2);
#pragma unroll
        for (int nf = 0; nf < 4; ++nf) {
            int oc = wn * 64 + nf * 16 + lr;
            float* po = out + (((size_t)b * OC + oc) * OH2 + oy) * OH2 + ox0;
            if (ox0 + 3 < OH2) {
                *(f32x4u*)po = acc[mf][nf];
            } else {
#pragma unroll
                for (int rr = 0; rr < 4; ++rr)
                    if (ox0 + rr < OH2) po[rr] = acc[mf][nf][rr];
            }
        }
    }
}

// ---------------------------------------------------------------------------
extern "C" void kernel_launch(void* const* d_in, const int* in_sizes, int n_in,
                              void* d_out, int out_size, void* d_ws, size_t ws_size,
                              hipStream_t stream) {
    const float* x      = (const float*)d_in[0];
    const float* w_p    = (const float*)d_in[1];
    const float* b_p    = (const float*)d_in[2];
    const float* w_conv = (const float*)d_in[3];
    float* out = (float*)d_out;

    const size_t offElems = (size_t)B_ * 18 * HH * WW;          // f32
    const size_t xtElems  = (size_t)B_ * HH * WW * IC;          // f32 NHWC copy
    const size_t btElems  = (size_t)18 * 4 * 128 * 8;           // bf16
    const size_t xofElems = (size_t)XOF * 8 * XPAD * 8;         // bf16 per batch
    const size_t slack    = 16384;

    float* off = (float*)d_ws;
    float* xtb = off + offElems;
    unsigned short* Bt   = (unsigned short*)(xtb + xtElems);
    unsigned short* xoff = Bt + btElems;

    const size_t headBytes = (offElems + xtElems) * 4 + btElems * 2;
    const bool allBatch = ws_size >= headBytes + 4 * xofElems * 2 + slack;

    prep_w<<<(int)((btElems + 255) / 256), 256, 0, stream>>>(w_conv, Bt);
    nchw2nhwc<<<2048, 256, 0, stream>>>(x, xtb);
    offset_lds4<<<1024, 256, 0, stream>>>(x, w_p, b_p, off);

    if (allBatch) {
        int snwg = 12 * XOF * B_;                 // 18432
        sample_nhwc<<<snwg, 256, 0, stream>>>(xtb, off, xoff, 0, snwg);
        int cnwg = 3 * OH2 * B_;                  // 4584
        conv2_mfma<<<cnwg, 256, 0, stream>>>(xoff, Bt, out, 0, cnwg);
    } else {
        for (int b = 0; b < B_; ++b) {
            int snwg = 12 * XOF;                  // 4608
            sample_nhwc<<<snwg, 256, 0, stream>>>(xtb, off, xoff, b, snwg);
            int cnwg = 3 * OH2;                   // 1146
            conv2_mfma<<<cnwg, 256, 0, stream>>>(xoff, Bt, out, b, cnwg);
        }
    }
}

// Round 13
// 249.331 us; speedup vs baseline: 1.0610x; 1.0610x over previous
//
#include <hip/hip_runtime.h>
#include <hip/hip_bf16.h>

#define B_   4
#define IC   64
#define OC   128
#define HH   128
#define WW   128
#define HP   130      // padded H/W for sampling
#define XOF  384      // x_off spatial (128*3)
#define XPAD 388      // padded x-dim of granule layout
#define OH2  382      // final output spatial

typedef __attribute__((ext_vector_type(4))) float f32x4;
typedef __attribute__((ext_vector_type(8))) __bf16 bf16x8;
typedef __attribute__((ext_vector_type(8))) unsigned short us8;
typedef __attribute__((ext_vector_type(4), aligned(4))) float f32x4u;

__device__ __forceinline__ void gload16(const void* gsrc, void* ldst) {
    __builtin_amdgcn_global_load_lds(
        (const __attribute__((address_space(1))) void*)gsrc,
        (__attribute__((address_space(3))) void*)ldst, 16, 0, 0);
}

// counted vmcnt wait (literal N), memory clobber pins surrounding mem ops
#define WAITV(N) asm volatile("s_waitcnt vmcnt(" #N ")" ::: "memory")

// ---------------------------------------------------------------------------
// Kernel T (byte-identical to R11/R12): NCHW -> NHWC fp32 transpose of x.
// ---------------------------------------------------------------------------
__global__ __launch_bounds__(256) void nchw2nhwc(const float* __restrict__ x,
                                                 float* __restrict__ xt) {
    __shared__ float tile[64][33];
    int bid = blockIdx.x;              // 4*128*4 = 2048
    int xt4 = bid & 3;
    int y   = (bid >> 2) & 127;
    int b   = bid >> 9;
    int x0  = xt4 * 32;

    int t  = threadIdx.x;
    int xl = t & 31;
    int c8 = t >> 5;
#pragma unroll
    for (int it = 0; it < 8; ++it) {
        int c = it * 8 + c8;
        tile[c][xl] = x[(((size_t)b * IC + c) * HH + y) * WW + x0 + xl];
    }
    __syncthreads();
    int c  = t & 63;
    int xw = t >> 6;
#pragma unroll
    for (int it = 0; it < 8; ++it) {
        int xx = it * 4 + xw;
        xt[(((size_t)b * HH + y) * WW + x0 + xx) * IC + c] = tile[c][xx];
    }
}

// ---------------------------------------------------------------------------
// Kernel A v5 (byte-identical to R11/R12): offset conv, ic-split x4 + LDS
// reduce, readfirstlane-scalarized weight base.
// ---------------------------------------------------------------------------
__global__ __launch_bounds__(256) void offset_lds4(const float* __restrict__ x,
                                                   const float* __restrict__ w_p,
                                                   const float* __restrict__ b_p,
                                                   float* __restrict__ off) {
    __shared__ float part[4][64][18];

    int t   = threadIdx.x;
    int pxl = t & 63;
    int icq = t >> 6;                 // 0..3 == wave index
    int seg = blockIdx.x & 1;
    int row = blockIdx.x >> 1;
    int py  = row & 127;
    int b   = row >> 7;
    int px  = seg * 64 + pxl;
    int ic0 = __builtin_amdgcn_readfirstlane(icq << 4);   // wave-uniform SGPR

    float acc[18];
#pragma unroll
    for (int co = 0; co < 18; ++co) acc[co] = 0.f;

    const float* xb = x + ((size_t)b * IC + ic0) * HH * WW;

    for (int ci = 0; ci < 16; ++ci) {
        const float* xc = xb + (size_t)ci * HH * WW;
        float xv[9];
#pragma unroll
        for (int ky = 0; ky < 3; ++ky) {
            int yy = py + ky - 1;
            bool yok = (yy >= 0) && (yy < HH);
#pragma unroll
            for (int kx = 0; kx < 3; ++kx) {
                int xx = px + kx - 1;
                bool ok = yok && (xx >= 0) && (xx < WW);
                xv[ky * 3 + kx] = ok ? xc[yy * WW + xx] : 0.f;
            }
        }
#pragma unroll
        for (int co = 0; co < 18; ++co) {
            const float* wrow = w_p + ((size_t)co * IC + ic0 + ci) * 9;
            f32x4u w0 = *(const f32x4u*)wrow;
            f32x4u w1 = *(const f32x4u*)(wrow + 4);
            float  w8 = wrow[8];
            acc[co] = fmaf(w0.x, xv[0], acc[co]);
            acc[co] = fmaf(w0.y, xv[1], acc[co]);
            acc[co] = fmaf(w0.z, xv[2], acc[co]);
            acc[co] = fmaf(w0.w, xv[3], acc[co]);
            acc[co] = fmaf(w1.x, xv[4], acc[co]);
            acc[co] = fmaf(w1.y, xv[5], acc[co]);
            acc[co] = fmaf(w1.z, xv[6], acc[co]);
            acc[co] = fmaf(w1.w, xv[7], acc[co]);
            acc[co] = fmaf(w8,   xv[8], acc[co]);
        }
    }

#pragma unroll
    for (int co = 0; co < 18; ++co) part[icq][pxl][co] = acc[co];
    __syncthreads();

    for (int co = icq; co < 18; co += 4) {
        float s = b_p[co] + part[0][pxl][co] + part[1][pxl][co]
                          + part[2][pxl][co] + part[3][pxl][co];
        off[((size_t)b * 18 + co) * HH * WW + (size_t)py * WW + px] = s;
    }
}

// ---------------------------------------------------------------------------
// Kernel P (byte-identical): weights -> bf16 K-step tiles.
// ---------------------------------------------------------------------------
__global__ __launch_bounds__(256) void prep_w(const float* __restrict__ wc,
                                              unsigned short* __restrict__ Bt) {
    int t = blockIdx.x * 256 + threadIdx.x;
    if (t >= 18 * 4 * 128 * 8) return;
    int e  = t & 7;
    int oc = (t >> 3) & 127;
    int kg = (t >> 10) & 3;
    int s  = t >> 12;
    int ic = ((s & 1) << 5) + (kg << 3) + e;
    int kpos = s >> 1;
    int ky = kpos / 3, kx = kpos % 3;
    float v = wc[(((size_t)oc * IC + ic) * 3 + ky) * 3 + kx];
    __hip_bfloat16 h = __float2bfloat16(v);
    Bt[t] = reinterpret_cast<unsigned short&>(h);
}

// ---------------------------------------------------------------------------
// Kernel B v3 (byte-identical to R11/R12): bilinear sampling from NHWC x.
// ---------------------------------------------------------------------------
__global__ __launch_bounds__(256) void sample_nhwc(const float* __restrict__ xt,
                                                   const float* __restrict__ off,
                                                   unsigned short* __restrict__ xoff,
                                                   int b0, int nwg) {
    int orig = blockIdx.x;
    int chunk = nwg >> 3;
    int wg = (orig & 7) * chunk + (orig >> 3);

    int xtile = wg % 12;
    int tmp = wg / 12;
    int yy  = tmp % XOF;
    int bl  = tmp / XOF;
    int b   = b0 + bl;
    int xx0 = xtile * 32;

    int t  = threadIdx.x;
    int xl = t & 31;
    int cg = t >> 5;
    int xx = xx0 + xl;

    int j = xx / 3, kw = xx % 3;
    int i = yy / 3, kh = yy % 3;
    int n = kh * 3 + kw;

    const float* offb = off + (size_t)b * 18 * HH * WW + (size_t)i * WW + j;
    float offr = offb[(size_t)n * HH * WW];
    float offc = offb[(size_t)(n + 9) * HH * WW];

    float pr = (float)(i + kh) + offr;
    float pc = (float)(j + kw) + offc;

    float r0f = floorf(pr), c0f = floorf(pc);
    int r0 = min(max((int)r0f, 0), HP - 1);
    int c0 = min(max((int)c0f, 0), HP - 1);
    int r1 = min(max((int)(r0f + 1.f), 0), HP - 1);
    int c1 = min(max((int)(c0f + 1.f), 0), HP - 1);

    float prc = fminf(fmaxf(pr, 0.f), (float)(HP - 1));
    float pcc = fminf(fmaxf(pc, 0.f), (float)(HP - 1));

    float R0 = 1.f + ((float)r0 - prc);
    float R1 = 1.f - ((float)r1 - prc);
    float C0 = 1.f + ((float)c0 - pcc);
    float C1 = 1.f - ((float)c1 - pcc);

    int rr0 = r0 - 1, cc0 = c0 - 1, rr1 = r1 - 1, cc1 = c1 - 1;
    if (!(rr0 >= 0 && rr0 < HH)) R0 = 0.f;
    if (!(rr1 >= 0 && rr1 < HH)) R1 = 0.f;
    float C0m = (cc0 >= 0 && cc0 < WW) ? C0 : 0.f;
    float C1m = (cc1 >= 0 && cc1 < WW) ? C1 : 0.f;
    int ra0 = min(max(rr0, 0), HH - 1);
    int ra1 = min(max(rr1, 0), HH - 1);
    int ca0 = min(max(cc0, 0), WW - 1);
    int ca1 = min(max(cc1, 0), WW - 1);

    const float* xb = xt + (size_t)b * HH * WW * IC + cg * 8;
    const float* p00 = xb + ((size_t)ra0 * WW + ca0) * IC;
    const float* p01 = xb + ((size_t)ra0 * WW + ca1) * IC;
    const float* p10 = xb + ((size_t)ra1 * WW + ca0) * IC;
    const float* p11 = xb + ((size_t)ra1 * WW + ca1) * IC;

    us8 res;
#pragma unroll
    for (int h = 0; h < 2; ++h) {
        f32x4u a  = *(const f32x4u*)(p00 + h * 4);
        f32x4u bb = *(const f32x4u*)(p01 + h * 4);
        f32x4u cc = *(const f32x4u*)(p10 + h * 4);
        f32x4u dd = *(const f32x4u*)(p11 + h * 4);
#pragma unroll
        for (int e = 0; e < 4; ++e) {
            float v = R0 * (C0m * a[e] + C1m * bb[e]) +
                      R1 * (C0m * cc[e] + C1m * dd[e]);
            __hip_bfloat16 hh = __float2bfloat16(v);
            res[h * 4 + e] = reinterpret_cast<unsigned short&>(hh);
        }
    }

    size_t di = ((((size_t)bl * XOF + yy) * 8 + cg) * XPAD + xx) * 8;
    *(us8*)(xoff + di) = res;
}

// ---------------------------------------------------------------------------
// Kernel C v7: v4's proven shared-staging structure (40KB dbuf, measured
// 154us) with T4 counted-vmcnt sync: raw s_barrier + literal vmcnt(N) that
// keeps tile t+1's loads IN FLIGHT across both barriers (no vmcnt(0) drain,
// the m97-structure stall). Per-wave load issue is symmetric (2 B + 1 A per
// step), so own-count + barrier => all waves' tile-t loads landed.
// ---------------------------------------------------------------------------
__global__ __launch_bounds__(256) void conv2_mfma(const unsigned short* __restrict__ xoff,
                                                  const unsigned short* __restrict__ Bt,
                                                  float* __restrict__ out,
                                                  int b0, int nwg) {
    __shared__ __align__(16) char lds[40960];
    // A slab buf: [cg:4][px:192][16B] = 12288 B at abuf*12288
    // B buf:      [kg:4][oc:128][16B] =  8192 B at 24576 + bbuf*8192

    // bijective XCD-chunk swizzle (m204)
    int orig = blockIdx.x;
    int q = nwg >> 3, r = nwg & 7;
    int xcd = orig & 7, loc = orig >> 3;
    int wgid = (xcd < r ? xcd * (q + 1) : r * (q + 1) + (xcd - r) * q) + loc;

    int xt  = wgid % 3;
    int tmp = wgid / 3;
    int oy  = tmp % OH2;
    int bl  = tmp / OH2;
    int x0  = xt << 7;

    int tid  = threadIdx.x;
    int wave = tid >> 6, lane = tid & 63;
    int wm = wave >> 1;            // px half
    int wn = wave & 1;             // oc half
    int lr = lane & 15, lc = lane >> 4;

    const char* xb = (const char*)xoff + (size_t)bl * ((size_t)XOF * 8 * XPAD * 16);
    const char* bt = (const char*)Bt;

    f32x4 acc[4][4];
#pragma unroll
    for (int mf = 0; mf < 4; ++mf)
#pragma unroll
        for (int nf = 0; nf < 4; ++nf)
            acc[mf][nf] = (f32x4){0.f, 0.f, 0.f, 0.f};

    // one third of the A slab for super-step s6: 4 loads, 1 per wave.
    auto stageA = [&](int abuf, int s6, int third) {
        int ky  = s6 >> 1;
        int ich = s6 & 1;
        int L   = third * 4 + wave;
        int cg  = L / 3, seg = L % 3;
        const char* src = xb +
            (((size_t)(oy + ky) * 8 + ich * 4 + cg) * XPAD + x0 + seg * 64 + lane) * 16;
        char* dst = lds + abuf * 12288 + (cg * 192 + seg * 64) * 16;
        gload16(src, dst);
    };
    // full slab (prologue): 12 loads, 3 per wave
    auto stageA_full = [&](int abuf, int s6) {
#pragma unroll
        for (int qq = 0; qq < 3; ++qq) {
            int ky  = s6 >> 1;
            int ich = s6 & 1;
            int L   = wave * 3 + qq;
            int cg  = L / 3, seg = L % 3;
            const char* src = xb +
                (((size_t)(oy + ky) * 8 + ich * 4 + cg) * XPAD + x0 + seg * 64 + lane) * 16;
            char* dst = lds + abuf * 12288 + (cg * 192 + seg * 64) * 16;
            gload16(src, dst);
        }
    };
    auto stageB = [&](int bbuf, int t) {
        int s6 = t / 3, kx = t % 3;
        int sB = ((s6 >> 1) * 3 + kx) * 2 + (s6 & 1);
        const char* bsrc = bt + (size_t)sB * 8192;
#pragma unroll
        for (int g2 = 0; g2 < 2; ++g2) {
            int g = wave * 2 + g2;
            gload16(bsrc + (size_t)g * 1024 + lane * 16,
                    lds + 24576 + bbuf * 8192 + g * 1024);
        }
    };

    auto compute = [&](int abuf, int bbuf, int kx) {
        const char* abase = lds + abuf * 12288;
        const char* bbase = lds + 24576 + bbuf * 8192;
        bf16x8 af[4], bfr[4];
#pragma unroll
        for (int mf = 0; mf < 4; ++mf)
            af[mf] = *(const bf16x8*)(abase +
                (lc * 192 + wm * 64 + mf * 16 + lr + kx) * 16);
#pragma unroll
        for (int nf = 0; nf < 4; ++nf)
            bfr[nf] = *(const bf16x8*)(bbase +
                (lc * 128 + wn * 64 + nf * 16 + lr) * 16);
#pragma unroll
        for (int mf = 0; mf < 4; ++mf)
#pragma unroll
            for (int nf = 0; nf < 4; ++nf)
                acc[mf][nf] = __builtin_amdgcn_mfma_f32_16x16x32_bf16(
                    af[mf], bfr[nf], acc[mf][nf], 0, 0, 0);
    };

    // prologue: 5 loads/wave in flight
    stageA_full(0, 0);
    stageB(0, 0);

    int abuf = 0, bbuf = 0;
#pragma unroll
    for (int s6 = 0; s6 < 6; ++s6) {
#pragma unroll
        for (int kx = 0; kx < 3; ++kx) {
            const int t = s6 * 3 + kx;
            // issue next-tile loads (stay in flight across the barriers)
            if (t + 1 < 18) stageB(bbuf ^ 1, t + 1);       // 2 loads
            if (s6 + 1 < 6) stageA(abuf ^ 1, s6 + 1, kx);  // 1 load
            // counted wait: drain only tile-t loads, keep t+1's flying
            if (s6 < 5)          { WAITV(3); }
            else if (kx < 2)     { WAITV(2); }
            else                 { WAITV(0); }
            __builtin_amdgcn_s_barrier();          // all waves' tile-t landed
            __builtin_amdgcn_sched_barrier(0);     // no ds_read hoist above
            compute(abuf, bbuf, kx);
            __builtin_amdgcn_sched_barrier(0);     // no ds_read sink below
            __builtin_amdgcn_s_barrier();          // buffer-reuse protection
            bbuf ^= 1;
        }
        abuf ^= 1;
    }

    int b = b0 + bl;
#pragma unroll
    for (int mf = 0; mf < 4; ++mf) {
        int ox0 = x0 + wm * 64 + mf * 16 + (lc << 2);
#pragma unroll
        for (int nf = 0; nf < 4; ++nf) {
            int oc = wn * 64 + nf * 16 + lr;
            float* po = out + (((size_t)b * OC + oc) * OH2 + oy) * OH2 + ox0;
            if (ox0 + 3 < OH2) {
                *(f32x4u*)po = acc[mf][nf];
            } else {
#pragma unroll
                for (int rr = 0; rr < 4; ++rr)
                    if (ox0 + rr < OH2) po[rr] = acc[mf][nf][rr];
            }
        }
    }
}

// ---------------------------------------------------------------------------
extern "C" void kernel_launch(void* const* d_in, const int* in_sizes, int n_in,
                              void* d_out, int out_size, void* d_ws, size_t ws_size,
                              hipStream_t stream) {
    const float* x      = (const float*)d_in[0];
    const float* w_p    = (const float*)d_in[1];
    const float* b_p    = (const float*)d_in[2];
    const float* w_conv = (const float*)d_in[3];
    float* out = (float*)d_out;

    const size_t offElems = (size_t)B_ * 18 * HH * WW;          // f32
    const size_t xtElems  = (size_t)B_ * HH * WW * IC;          // f32 NHWC copy
    const size_t btElems  = (size_t)18 * 4 * 128 * 8;           // bf16
    const size_t xofElems = (size_t)XOF * 8 * XPAD * 8;         // bf16 per batch
    const size_t slack    = 16384;

    float* off = (float*)d_ws;
    float* xtb = off + offElems;
    unsigned short* Bt   = (unsigned short*)(xtb + xtElems);
    unsigned short* xoff = Bt + btElems;

    const size_t headBytes = (offElems + xtElems) * 4 + btElems * 2;
    const bool allBatch = ws_size >= headBytes + 4 * xofElems * 2 + slack;

    prep_w<<<(int)((btElems + 255) / 256), 256, 0, stream>>>(w_conv, Bt);
    nchw2nhwc<<<2048, 256, 0, stream>>>(x, xtb);
    offset_lds4<<<1024, 256, 0, stream>>>(x, w_p, b_p, off);

    if (allBatch) {
        int snwg = 12 * XOF * B_;                 // 18432
        sample_nhwc<<<snwg, 256, 0, stream>>>(xtb, off, xoff, 0, snwg);
        int cnwg = 3 * OH2 * B_;                  // 4584
        conv2_mfma<<<cnwg, 256, 0, stream>>>(xoff, Bt, out, 0, cnwg);
    } else {
        for (int b = 0; b < B_; ++b) {
            int snwg = 12 * XOF;                  // 4608
            sample_nhwc<<<snwg, 256, 0, stream>>>(xtb, off, xoff, b, snwg);
            int cnwg = 3 * OH2;                   // 1146
            conv2_mfma<<<cnwg, 256, 0, stream>>>(xoff, Bt, out, b, cnwg);
        }
    }
}

// Round 14
// 228.496 us; speedup vs baseline: 1.1578x; 1.0912x over previous
//
#include <hip/hip_runtime.h>
#include <hip/hip_bf16.h>

#define B_   4
#define IC   64
#define OC   128
#define HH   128
#define WW   128
#define HP   130      // padded H/W for sampling
#define XOF  384      // x_off spatial (128*3)
#define XPAD 388      // padded x-dim of granule layout
#define OH2  382      // final output spatial

typedef __attribute__((ext_vector_type(4))) float f32x4;
typedef __attribute__((ext_vector_type(8))) __bf16 bf16x8;
typedef __attribute__((ext_vector_type(8))) unsigned short us8;
typedef __attribute__((ext_vector_type(4), aligned(4))) float f32x4u;

__device__ __forceinline__ void gload16(const void* gsrc, void* ldst) {
    __builtin_amdgcn_global_load_lds(
        (const __attribute__((address_space(1))) void*)gsrc,
        (__attribute__((address_space(3))) void*)ldst, 16, 0, 0);
}

#define WAITV(N) asm volatile("s_waitcnt vmcnt(" #N ")" ::: "memory")

__device__ __forceinline__ float bf2f(unsigned short u) {
    union { unsigned int i; float f; } v; v.i = ((unsigned int)u) << 16; return v.f;
}
__device__ __forceinline__ unsigned short f2bf(float f) {
    __hip_bfloat16 h = __float2bfloat16(f);
    return reinterpret_cast<unsigned short&>(h);
}

// ---------------------------------------------------------------------------
// FUSED PROLOGUE: three independent preprocessing jobs in one dispatch.
//   bid in [0,2048):      NCHW -> NHWC *bf16* transpose of x  (halved bytes)
//   bid in [2048,3072):   offset conv (ic-split x4 + LDS reduce, rfl weights)
//   bid in [3072,3360):   w_conv -> bf16 K-step tiles Bt
// ---------------------------------------------------------------------------
__global__ __launch_bounds__(256) void prologue(const float* __restrict__ x,
                                                const float* __restrict__ w_p,
                                                const float* __restrict__ b_p,
                                                const float* __restrict__ wc,
                                                float* __restrict__ off,
                                                unsigned short* __restrict__ xt,
                                                unsigned short* __restrict__ Bt) {
    __shared__ __align__(16) char smem[18432];
    int bid = blockIdx.x;
    int tid = threadIdx.x;

    if (bid < 2048) {
        // ---- transpose to bf16 NHWC ----
        unsigned short (*tile)[34] = (unsigned short(*)[34])smem;  // 64x34 ushort
        int xt4 = bid & 3;
        int y   = (bid >> 2) & 127;
        int b   = bid >> 9;
        int x0  = xt4 * 32;

        int xl = tid & 31;
        int c8 = tid >> 5;
#pragma unroll
        for (int it = 0; it < 8; ++it) {
            int c = it * 8 + c8;
            tile[c][xl] = f2bf(x[(((size_t)b * IC + c) * HH + y) * WW + x0 + xl]);
        }
        __syncthreads();
        int c2 = (tid & 31) * 2;
#pragma unroll
        for (int it = 0; it < 4; ++it) {
            int xx = (tid >> 5) + it * 8;
            ushort2 v = { tile[c2][xx], tile[c2 + 1][xx] };
            *(ushort2*)(xt + (((size_t)b * HH + y) * WW + x0 + xx) * IC + c2) = v;
        }
    } else if (bid < 3072) {
        // ---- offset conv ----
        float (*part)[64][18] = (float(*)[64][18])smem;   // 4x64x18 f32
        int obid = bid - 2048;
        int pxl = tid & 63;
        int icq = tid >> 6;
        int seg = obid & 1;
        int row = obid >> 1;
        int py  = row & 127;
        int b   = row >> 7;
        int px  = seg * 64 + pxl;
        int ic0 = __builtin_amdgcn_readfirstlane(icq << 4);

        float acc[18];
#pragma unroll
        for (int co = 0; co < 18; ++co) acc[co] = 0.f;

        const float* xb = x + ((size_t)b * IC + ic0) * HH * WW;

        for (int ci = 0; ci < 16; ++ci) {
            const float* xc = xb + (size_t)ci * HH * WW;
            float xv[9];
#pragma unroll
            for (int ky = 0; ky < 3; ++ky) {
                int yy = py + ky - 1;
                bool yok = (yy >= 0) && (yy < HH);
#pragma unroll
                for (int kx = 0; kx < 3; ++kx) {
                    int xx = px + kx - 1;
                    bool ok = yok && (xx >= 0) && (xx < WW);
                    xv[ky * 3 + kx] = ok ? xc[yy * WW + xx] : 0.f;
                }
            }
#pragma unroll
            for (int co = 0; co < 18; ++co) {
                const float* wrow = w_p + ((size_t)co * IC + ic0 + ci) * 9;
                f32x4u w0 = *(const f32x4u*)wrow;
                f32x4u w1 = *(const f32x4u*)(wrow + 4);
                float  w8 = wrow[8];
                acc[co] = fmaf(w0.x, xv[0], acc[co]);
                acc[co] = fmaf(w0.y, xv[1], acc[co]);
                acc[co] = fmaf(w0.z, xv[2], acc[co]);
                acc[co] = fmaf(w0.w, xv[3], acc[co]);
                acc[co] = fmaf(w1.x, xv[4], acc[co]);
                acc[co] = fmaf(w1.y, xv[5], acc[co]);
                acc[co] = fmaf(w1.z, xv[6], acc[co]);
                acc[co] = fmaf(w1.w, xv[7], acc[co]);
                acc[co] = fmaf(w8,   xv[8], acc[co]);
            }
        }

#pragma unroll
        for (int co = 0; co < 18; ++co) part[icq][pxl][co] = acc[co];
        __syncthreads();

        for (int co = icq; co < 18; co += 4) {
            float s = b_p[co] + part[0][pxl][co] + part[1][pxl][co]
                              + part[2][pxl][co] + part[3][pxl][co];
            off[((size_t)b * 18 + co) * HH * WW + (size_t)py * WW + px] = s;
        }
    } else {
        // ---- prep_w ----
        int t = (bid - 3072) * 256 + tid;
        if (t < 18 * 4 * 128 * 8) {
            int e  = t & 7;
            int oc = (t >> 3) & 127;
            int kg = (t >> 10) & 3;
            int s  = t >> 12;
            int ic = ((s & 1) << 5) + (kg << 3) + e;
            int kpos = s >> 1;
            int ky = kpos / 3, kx = kpos % 3;
            Bt[t] = f2bf(wc[(((size_t)oc * IC + ic) * 3 + ky) * 3 + kx]);
        }
    }
}

// ---------------------------------------------------------------------------
// Kernel B v4: bilinear sampling from *bf16* NHWC xt. One 16B load per
// (corner, granule) -> 4 gathers/thread instead of 8 (VMEM-issue bound path
// halved). Same lerp formula per element; inputs pre-rounded to bf16.
// ---------------------------------------------------------------------------
__global__ __launch_bounds__(256) void sample_nhwc(const unsigned short* __restrict__ xt,
                                                   const float* __restrict__ off,
                                                   unsigned short* __restrict__ xoff,
                                                   int b0, int nwg) {
    int orig = blockIdx.x;
    int chunk = nwg >> 3;
    int wg = (orig & 7) * chunk + (orig >> 3);

    int xtile = wg % 12;
    int tmp = wg / 12;
    int yy  = tmp % XOF;
    int bl  = tmp / XOF;
    int b   = b0 + bl;
    int xx0 = xtile * 32;

    int t  = threadIdx.x;
    int xl = t & 31;
    int cg = t >> 5;
    int xx = xx0 + xl;

    int j = xx / 3, kw = xx % 3;
    int i = yy / 3, kh = yy % 3;
    int n = kh * 3 + kw;

    const float* offb = off + (size_t)b * 18 * HH * WW + (size_t)i * WW + j;
    float offr = offb[(size_t)n * HH * WW];
    float offc = offb[(size_t)(n + 9) * HH * WW];

    float pr = (float)(i + kh) + offr;
    float pc = (float)(j + kw) + offc;

    float r0f = floorf(pr), c0f = floorf(pc);
    int r0 = min(max((int)r0f, 0), HP - 1);
    int c0 = min(max((int)c0f, 0), HP - 1);
    int r1 = min(max((int)(r0f + 1.f), 0), HP - 1);
    int c1 = min(max((int)(c0f + 1.f), 0), HP - 1);

    float prc = fminf(fmaxf(pr, 0.f), (float)(HP - 1));
    float pcc = fminf(fmaxf(pc, 0.f), (float)(HP - 1));

    float R0 = 1.f + ((float)r0 - prc);
    float R1 = 1.f - ((float)r1 - prc);
    float C0 = 1.f + ((float)c0 - pcc);
    float C1 = 1.f - ((float)c1 - pcc);

    int rr0 = r0 - 1, cc0 = c0 - 1, rr1 = r1 - 1, cc1 = c1 - 1;
    if (!(rr0 >= 0 && rr0 < HH)) R0 = 0.f;
    if (!(rr1 >= 0 && rr1 < HH)) R1 = 0.f;
    float C0m = (cc0 >= 0 && cc0 < WW) ? C0 : 0.f;
    float C1m = (cc1 >= 0 && cc1 < WW) ? C1 : 0.f;
    int ra0 = min(max(rr0, 0), HH - 1);
    int ra1 = min(max(rr1, 0), HH - 1);
    int ca0 = min(max(cc0, 0), WW - 1);
    int ca1 = min(max(cc1, 0), WW - 1);

    const unsigned short* xb = xt + (size_t)b * HH * WW * IC + cg * 8;
    us8 a  = *(const us8*)(xb + ((size_t)ra0 * WW + ca0) * IC);
    us8 bb = *(const us8*)(xb + ((size_t)ra0 * WW + ca1) * IC);
    us8 cc = *(const us8*)(xb + ((size_t)ra1 * WW + ca0) * IC);
    us8 dd = *(const us8*)(xb + ((size_t)ra1 * WW + ca1) * IC);

    us8 res;
#pragma unroll
    for (int e = 0; e < 8; ++e) {
        float v = R0 * (C0m * bf2f(a[e]) + C1m * bf2f(bb[e])) +
                  R1 * (C0m * bf2f(cc[e]) + C1m * bf2f(dd[e]));
        res[e] = f2bf(v);
    }

    size_t di = ((((size_t)bl * XOF + yy) * 8 + cg) * XPAD + xx) * 8;
    *(us8*)(xoff + di) = res;
}

// ---------------------------------------------------------------------------
// Kernel C v8: v7 (counted-vmcnt, 2-barrier) + T5 s_setprio around the MFMA
// cluster. Counted waits keep next-tile loads in flight across barriers.
// ---------------------------------------------------------------------------
__global__ __launch_bounds__(256) void conv2_mfma(const unsigned short* __restrict__ xoff,
                                                  const unsigned short* __restrict__ Bt,
                                                  float* __restrict__ out,
                                                  int b0, int nwg) {
    __shared__ __align__(16) char lds[40960];
    // A slab buf: [cg:4][px:192][16B] = 12288 B at abuf*12288
    // B buf:      [kg:4][oc:128][16B] =  8192 B at 24576 + bbuf*8192

    int orig = blockIdx.x;
    int q = nwg >> 3, r = nwg & 7;
    int xcd = orig & 7, loc = orig >> 3;
    int wgid = (xcd < r ? xcd * (q + 1) : r * (q + 1) + (xcd - r) * q) + loc;

    int xt  = wgid % 3;
    int tmp = wgid / 3;
    int oy  = tmp % OH2;
    int bl  = tmp / OH2;
    int x0  = xt << 7;

    int tid  = threadIdx.x;
    int wave = tid >> 6, lane = tid & 63;
    int wm = wave >> 1;            // px half
    int wn = wave & 1;             // oc half
    int lr = lane & 15, lc = lane >> 4;

    const char* xb = (const char*)xoff + (size_t)bl * ((size_t)XOF * 8 * XPAD * 16);
    const char* bt = (const char*)Bt;

    f32x4 acc[4][4];
#pragma unroll
    for (int mf = 0; mf < 4; ++mf)
#pragma unroll
        for (int nf = 0; nf < 4; ++nf)
            acc[mf][nf] = (f32x4){0.f, 0.f, 0.f, 0.f};

    auto stageA = [&](int abuf, int s6, int third) {
        int ky  = s6 >> 1;
        int ich = s6 & 1;
        int L   = third * 4 + wave;
        int cg  = L / 3, seg = L % 3;
        const char* src = xb +
            (((size_t)(oy + ky) * 8 + ich * 4 + cg) * XPAD + x0 + seg * 64 + lane) * 16;
        char* dst = lds + abuf * 12288 + (cg * 192 + seg * 64) * 16;
        gload16(src, dst);
    };
    auto stageA_full = [&](int abuf, int s6) {
#pragma unroll
        for (int qq = 0; qq < 3; ++qq) {
            int ky  = s6 >> 1;
            int ich = s6 & 1;
            int L   = wave * 3 + qq;
            int cg  = L / 3, seg = L % 3;
            const char* src = xb +
                (((size_t)(oy + ky) * 8 + ich * 4 + cg) * XPAD + x0 + seg * 64 + lane) * 16;
            char* dst = lds + abuf * 12288 + (cg * 192 + seg * 64) * 16;
            gload16(src, dst);
        }
    };
    auto stageB = [&](int bbuf, int t) {
        int s6 = t / 3, kx = t % 3;
        int sB = ((s6 >> 1) * 3 + kx) * 2 + (s6 & 1);
        const char* bsrc = bt + (size_t)sB * 8192;
#pragma unroll
        for (int g2 = 0; g2 < 2; ++g2) {
            int g = wave * 2 + g2;
            gload16(bsrc + (size_t)g * 1024 + lane * 16,
                    lds + 24576 + bbuf * 8192 + g * 1024);
        }
    };

    auto compute = [&](int abuf, int bbuf, int kx) {
        const char* abase = lds + abuf * 12288;
        const char* bbase = lds + 24576 + bbuf * 8192;
        bf16x8 af[4], bfr[4];
#pragma unroll
        for (int mf = 0; mf < 4; ++mf)
            af[mf] = *(const bf16x8*)(abase +
                (lc * 192 + wm * 64 + mf * 16 + lr + kx) * 16);
#pragma unroll
        for (int nf = 0; nf < 4; ++nf)
            bfr[nf] = *(const bf16x8*)(bbase +
                (lc * 128 + wn * 64 + nf * 16 + lr) * 16);
        __builtin_amdgcn_s_setprio(1);
#pragma unroll
        for (int mf = 0; mf < 4; ++mf)
#pragma unroll
            for (int nf = 0; nf < 4; ++nf)
                acc[mf][nf] = __builtin_amdgcn_mfma_f32_16x16x32_bf16(
                    af[mf], bfr[nf], acc[mf][nf], 0, 0, 0);
        __builtin_amdgcn_s_setprio(0);
    };

    stageA_full(0, 0);
    stageB(0, 0);

    int abuf = 0, bbuf = 0;
#pragma unroll
    for (int s6 = 0; s6 < 6; ++s6) {
#pragma unroll
        for (int kx = 0; kx < 3; ++kx) {
            const int t = s6 * 3 + kx;
            if (t + 1 < 18) stageB(bbuf ^ 1, t + 1);       // 2 loads
            if (s6 + 1 < 6) stageA(abuf ^ 1, s6 + 1, kx);  // 1 load
            if (s6 < 5)          { WAITV(3); }
            else if (kx < 2)     { WAITV(2); }
            else                 { WAITV(0); }
            __builtin_amdgcn_s_barrier();
            __builtin_amdgcn_sched_barrier(0);
            compute(abuf, bbuf, kx);
            __builtin_amdgcn_sched_barrier(0);
            __builtin_amdgcn_s_barrier();
            bbuf ^= 1;
        }
        abuf ^= 1;
    }

    int b = b0 + bl;
#pragma unroll
    for (int mf = 0; mf < 4; ++mf) {
        int ox0 = x0 + wm * 64 + mf * 16 + (lc << 2);
#pragma unroll
        for (int nf = 0; nf < 4; ++nf) {
            int oc = wn * 64 + nf * 16 + lr;
            float* po = out + (((size_t)b * OC + oc) * OH2 + oy) * OH2 + ox0;
            if (ox0 + 3 < OH2) {
                *(f32x4u*)po = acc[mf][nf];
            } else {
#pragma unroll
                for (int rr = 0; rr < 4; ++rr)
                    if (ox0 + rr < OH2) po[rr] = acc[mf][nf][rr];
            }
        }
    }
}

// ---------------------------------------------------------------------------
extern "C" void kernel_launch(void* const* d_in, const int* in_sizes, int n_in,
                              void* d_out, int out_size, void* d_ws, size_t ws_size,
                              hipStream_t stream) {
    const float* x      = (const float*)d_in[0];
    const float* w_p    = (const float*)d_in[1];
    const float* b_p    = (const float*)d_in[2];
    const float* w_conv = (const float*)d_in[3];
    float* out = (float*)d_out;

    const size_t offElems = (size_t)B_ * 18 * HH * WW;          // f32
    const size_t xtElems  = (size_t)B_ * HH * WW * IC;          // bf16 NHWC copy
    const size_t btElems  = (size_t)18 * 4 * 128 * 8;           // bf16
    const size_t xofElems = (size_t)XOF * 8 * XPAD * 8;         // bf16 per batch
    const size_t slack    = 16384;

    float* off = (float*)d_ws;
    unsigned short* xtb  = (unsigned short*)(off + offElems);
    unsigned short* Bt   = xtb + xtElems;
    unsigned short* xoff = Bt + btElems;

    const size_t headBytes = offElems * 4 + (xtElems + btElems) * 2;
    const bool allBatch = ws_size >= headBytes + 4 * xofElems * 2 + slack;

    prologue<<<3360, 256, 0, stream>>>(x, w_p, b_p, w_conv, off, xtb, Bt);

    if (allBatch) {
        int snwg = 12 * XOF * B_;                 // 18432
        sample_nhwc<<<snwg, 256, 0, stream>>>(xtb, off, xoff, 0, snwg);
        int cnwg = 3 * OH2 * B_;                  // 4584
        conv2_mfma<<<cnwg, 256, 0, stream>>>(xoff, Bt, out, 0, cnwg);
    } else {
        for (int b = 0; b < B_; ++b) {
            int snwg = 12 * XOF;                  // 4608
            sample_nhwc<<<snwg, 256, 0, stream>>>(xtb, off, xoff, b, snwg);
            int cnwg = 3 * OH2;                   // 1146
            conv2_mfma<<<cnwg, 256, 0, stream>>>(xoff, Bt, out, b, cnwg);
        }
    }
}